// Round 1
// baseline (78.284 us; speedup 1.0000x reference)
//
#include <hip/hip_runtime.h>

// FieldWeightedFactorizationMachine forward.
// B=32768 rows; F=39 fields; D=64 dims; V=1e6 vocab.
// One 64-lane wave per row: lane = dim d. v[i] = emb[x[row,i]][d].
// interactions(d) = sum_{i<j} W[i,j] * v[i] * v[j]; wave-reduce over d.

#define FW_B 32768
#define FW_F 39
#define FW_D 64

__global__ __launch_bounds__(256) void fwfm_kernel(
    const int*   __restrict__ x,      // (B, F)
    const float* __restrict__ emb,    // (V, D)
    const float* __restrict__ bias,   // (V, 1)
    const float* __restrict__ W,      // (F, F)
    const float* __restrict__ w0,     // (1,)
    float*       __restrict__ out)    // (B,)
{
    const int wave = threadIdx.x >> 6;            // 0..3
    const int lane = threadIdx.x & 63;            // dim d
    const int row  = blockIdx.x * 4 + wave;
    if (row >= FW_B) return;

    // Field indices for this row — wave-uniform (same address across lanes).
    int idx[FW_F];
    #pragma unroll
    for (int i = 0; i < FW_F; ++i) idx[i] = x[row * FW_F + i];

    // Gather embeddings: coalesced — 64 lanes read one contiguous 256B row.
    float v[FW_F];
    #pragma unroll
    for (int i = 0; i < FW_F; ++i) {
        v[i] = emb[idx[i] * FW_D + lane];          // idx*64+lane < 6.4e7, int ok
    }

    // Bias sum — wave-uniform loads (broadcast; 4MB table, mostly L2-resident).
    float bsum = 0.0f;
    #pragma unroll
    for (int i = 0; i < FW_F; ++i) bsum += bias[idx[i]];

    // Upper-triangular weighted pairwise products for this lane's dim.
    // W reads are wave-uniform with compile-time offsets -> scalar loads.
    float acc = 0.0f;
    #pragma unroll
    for (int i = 0; i < FW_F - 1; ++i) {
        float s = 0.0f;
        #pragma unroll
        for (int j = i + 1; j < FW_F; ++j)
            s = fmaf(W[i * FW_F + j], v[j], s);
        acc = fmaf(v[i], s, acc);
    }

    // Reduce interactions over the 64 dims.
    #pragma unroll
    for (int off = 32; off >= 1; off >>= 1)
        acc += __shfl_xor(acc, off, 64);

    if (lane == 0)
        out[row] = w0[0] + bsum + acc;
}

extern "C" void kernel_launch(void* const* d_in, const int* in_sizes, int n_in,
                              void* d_out, int out_size, void* d_ws, size_t ws_size,
                              hipStream_t stream) {
    const int*   x    = (const int*)  d_in[0];
    const float* emb  = (const float*)d_in[1];
    const float* bias = (const float*)d_in[2];
    const float* W    = (const float*)d_in[3];
    const float* w0   = (const float*)d_in[4];
    float* out        = (float*)d_out;

    const int rows_per_block = 4;                  // 4 waves x 64 lanes
    const int grid = (FW_B + rows_per_block - 1) / rows_per_block;
    fwfm_kernel<<<grid, 256, 0, stream>>>(x, emb, bias, W, w0, out);
}